// Round 13
// baseline (137.317 us; speedup 1.0000x reference)
//
#include <hip/hip_runtime.h>
#include <hip/hip_bf16.h>

// Problem shape (fixed by setup_inputs): B=8, Q=2048 -> N=16384 rows,
// D=1024, Dp=256, K=2048 prototypes.
#define N_ROWS 16384
#define DIM    1024
#define DP     256
#define NPROTO 2048

typedef float f32x4 __attribute__((ext_vector_type(4)));
typedef short s16x8 __attribute__((ext_vector_type(8)));
typedef short s16x4 __attribute__((ext_vector_type(4)));

__device__ __forceinline__ unsigned short f2bf(float f) {
  __hip_bfloat16 h = __float2bfloat16(f);   // RNE
  return __builtin_bit_cast(unsigned short, h);
}

// LDS-only barrier (no vmcnt drain; global prefetches stay in flight).
__device__ __forceinline__ void lds_barrier() {
  asm volatile("s_waitcnt lgkmcnt(0)" ::: "memory");
  __builtin_amdgcn_s_barrier();
}

// ---- prep: build FRAGMENT-ORDER operands ----
// projT_sw[cg][kb][lane][8]: cg in [0,16), kb in [0,32);
//   lane's 8 bf16 = proj[kb*32+(lane>>4)*8+j][cg*16+(lane&15)].
// Pb_sw[pgrp][kb][lane][8]: pgrp in [0,128), kb in [0,8);
//   lane's 8 bf16 = proto[pgrp*16+(lane&15)][kb*32+(lane>>4)*8+j].
// A wave's MFMA B-fragment load is then base + lane*16B: one coalesced 1KB read.
__global__ void k_prep(const float* __restrict__ proj,
                       const float* __restrict__ P,
                       unsigned short* __restrict__ projT_sw,
                       unsigned short* __restrict__ Pb_sw,
                       float* __restrict__ pp) {
  int b = blockIdx.x;
  int t = threadIdx.x;
  if (b < 128) {                      // projT_sw: 32768 16B chunks
    int q    = b * 256 + t;
    int lane = q & 63, kb = (q >> 6) & 31, cg = q >> 11;
    int c  = cg * 16 + (lane & 15);
    int k0 = kb * 32 + (lane >> 4) * 8;
    s16x8 v;
#pragma unroll
    for (int j = 0; j < 8; ++j)
      v[j] = (short)f2bf(proj[(size_t)(k0 + j) * DP + c]);
    *(s16x8*)(projT_sw + (size_t)q * 8) = v;
  } else if (b < 384) {               // Pb_sw: 65536 16B chunks
    int q    = (b - 128) * 256 + t;
    int lane = q & 63, kb = (q >> 6) & 7, pg = q >> 9;
    const float* src = P + (size_t)(pg * 16 + (lane & 15)) * DP +
                       kb * 32 + (lane >> 4) * 8;
    s16x8 v;
#pragma unroll
    for (int j = 0; j < 8; ++j) v[j] = (short)f2bf(src[j]);
    *(s16x8*)(Pb_sw + (size_t)q * 8) = v;
  } else {                            // pp: one block per proto
    int k = b - 384;
    float v = P[(size_t)k * DP + t];
    float s = v * v;
#pragma unroll
    for (int o = 1; o < 64; o <<= 1) s += __shfl_xor(s, o, 64);
    __shared__ float ws4[4];
    if ((t & 63) == 0) ws4[t >> 6] = s;
    __syncthreads();
    if (t == 0) pp[k] = ws4[0] + ws4[1] + ws4[2] + ws4[3];
  }
}

// ---- FUSED: 64 rows/block, 1024 threads = 16 waves (4/SIMD), grid 256 = 1/CU ----
// Phase 1 (16 steps, BK=64): X staged via LDS (4-deep reg prefetch), each
//   wave owns ONE 16-col group (cg=wv); B reg-direct coalesced from
//   projT_sw, 4-deep. lds_barrier only (no vmcnt drain).
// Handoff: row norms across 16 waves, normalized Z -> Zs (3 lds_barriers).
// Phase 2 (ZERO barriers): wave owns ALL 64 rows x protos wv*128..+128
//   -> 8 MFMA per 2KB B-loads (2x R11 density), per-CU L2 traffic 1 MB.
//   A re-read per-ks from Zs; B 4-deep named prefetch; -sqrt streamed.
__global__ __launch_bounds__(1024, 4)
void k_fused(const float* __restrict__ X, const float* __restrict__ mean,
             const unsigned short* __restrict__ projT_sw,
             const unsigned short* __restrict__ Pb_sw,
             const float* __restrict__ pp, float* __restrict__ out) {
  __shared__ __align__(16) unsigned short Zs[64][264];   // 33792 B
  __shared__ __align__(16) unsigned short As[2][64][72]; // 18432 B
  __shared__ __align__(16) float mean_s[DIM];            //  4096 B
  __shared__ float rowsq[16][64];                        //  4096 B
  __shared__ float invs[64];                             //   256 B

  const int tid  = threadIdx.x;
  const int lane = tid & 63;
  const int wv   = tid >> 6;        // wave id 0..15
  const int l15  = lane & 15;
  const int lhi  = lane >> 4;
  const int rb   = blockIdx.x * 64;

  // stage mean once
  if (tid < 256)
    *(f32x4*)&mean_s[tid * 4] = *(const f32x4*)(mean + tid * 4);
  __syncthreads();

  // phase-1 staging coords: 64 rows x 64 cols = 1024 f32x4 -> 1/thread
  const int arow = tid >> 4;             // [0,64)
  const int ach  = (tid & 15) * 4;
  const float* xbase = X + (size_t)(rb + arow) * DIM + ach;
  // phase-1 B base: wave wv owns col-group cg = wv
  const unsigned short* pj_base =
      projT_sw + (size_t)wv * 32 * 512 + (size_t)lane * 8;

  f32x4 acc[4];                     // 4 mf x 1 cg
#pragma unroll
  for (int mf = 0; mf < 4; ++mf) acc[mf] = (f32x4)0.0f;

  f32x4 xA, xB, xC, xD;
  s16x8 bA[2], bB[2], bC[2], bD[2];

#define P1X(XR, T) { XR = *(const f32x4*)(xbase + (T) * 64); }
#define P1B(BR, T)                                                           \
  {                                                                          \
    BR[0] = *(const s16x8*)(pj_base + (size_t)((T) * 2 + 0) * 512);          \
    BR[1] = *(const s16x8*)(pj_base + (size_t)((T) * 2 + 1) * 512);          \
  }
#define P1W(CUR, XR, T)                                                      \
  {                                                                          \
    f32x4 m0 = *(const f32x4*)&mean_s[(T) * 64 + ach];                       \
    f32x4 c0 = XR - m0;                                                      \
    s16x4 v;                                                                 \
    v[0] = (short)f2bf(c0[0]); v[1] = (short)f2bf(c0[1]);                    \
    v[2] = (short)f2bf(c0[2]); v[3] = (short)f2bf(c0[3]);                    \
    *(s16x4*)(&As[CUR][arow][ach]) = v;                                      \
  }
#define P1C(CUR, BR)                                                         \
  {                                                                          \
    s16x8 a[4][2];                                                           \
    _Pragma("unroll")                                                        \
    for (int mf = 0; mf < 4; ++mf)                                           \
      _Pragma("unroll")                                                      \
      for (int kk = 0; kk < 2; ++kk)                                         \
        a[mf][kk] = *(const s16x8*)(&As[CUR][mf * 16 + l15][kk * 32 + lhi * 8]); \
    _Pragma("unroll")                                                        \
    for (int mf = 0; mf < 4; ++mf)                                           \
      _Pragma("unroll")                                                      \
      for (int kk = 0; kk < 2; ++kk)                                         \
        acc[mf] = __builtin_amdgcn_mfma_f32_16x16x32_bf16(                   \
            a[mf][kk], BR[kk], acc[mf], 0, 0, 0);                            \
  }
#define P1SUB(S, XR, BR)                                                     \
  {                                                                          \
    P1W((S) & 1, XR, S);                                                     \
    if ((S) + 4 < 16) P1X(XR, (S) + 4);                                      \
    lds_barrier();                                                           \
    P1C((S) & 1, BR);                                                        \
    if ((S) + 4 < 16) P1B(BR, (S) + 4);                                      \
  }

  P1X(xA, 0); P1B(bA, 0);
  P1X(xB, 1); P1B(bB, 1);
  P1X(xC, 2); P1B(bC, 2);
  P1X(xD, 3); P1B(bD, 3);
  for (int t = 0; t < 16; t += 4) {
    P1SUB(t + 0, xA, bA);
    P1SUB(t + 1, xB, bB);
    P1SUB(t + 2, xC, bC);
    P1SUB(t + 3, xD, bD);
  }
#undef P1X
#undef P1B
#undef P1W
#undef P1C
#undef P1SUB

  // issue phase-2 first B loads now (survive the handoff lds_barriers).
  // wave wv owns protos wv*128..+128 = proto-groups wv*8..+8.
  const unsigned short* pb_base =
      Pb_sw + (size_t)(wv * 8) * 8 * 512 + (size_t)lane * 8;
  s16x8 brA[2], brB[2], brC[2], brD[2];
#define P2B(REGS, T)                                                         \
  {                                                                          \
    const int g_ = (T) >> 3, k_ = (T) & 7;                                   \
    REGS[0] = *(const s16x8*)(pb_base + (size_t)((g_ * 2 + 0) * 8 + k_) * 512); \
    REGS[1] = *(const s16x8*)(pb_base + (size_t)((g_ * 2 + 1) * 8 + k_) * 512); \
  }
  P2B(brA, 0);
  P2B(brB, 1);
  P2B(brC, 2);
  P2B(brD, 3);

  // ---- handoff: row norms + normalized Z -> Zs ----
#pragma unroll
  for (int mf = 0; mf < 4; ++mf)
#pragma unroll
    for (int r = 0; r < 4; ++r) {
      float s = acc[mf][r] * acc[mf][r];
#pragma unroll
      for (int o = 1; o < 16; o <<= 1) s += __shfl_xor(s, o, 16);
      if (l15 == 0) rowsq[wv][mf * 16 + lhi * 4 + r] = s;
    }
  lds_barrier();
  if (tid < 64) {
    float n2 = 0.0f;
#pragma unroll
    for (int w = 0; w < 16; ++w) n2 += rowsq[w][tid];
    invs[tid] = 1.0f / fmaxf(sqrtf(n2), 1e-12f);  // F.normalize eps
  }
  lds_barrier();
#pragma unroll
  for (int mf = 0; mf < 4; ++mf)
#pragma unroll
    for (int r = 0; r < 4; ++r) {
      int row   = mf * 16 + lhi * 4 + r;
      float inv = invs[row];
      Zs[row][wv * 16 + l15] = f2bf(acc[mf][r] * inv);
    }
  lds_barrier();

  // ================= phase 2 (no barriers) =================
  const float* ppb = pp + wv * 128;
  float* outb = out + (size_t)rb * NPROTO + wv * 128;

#define P2KS(KS, G, REGS)                                                    \
  {                                                                          \
    s16x8 a[4];                                                              \
    _Pragma("unroll")                                                        \
    for (int mf = 0; mf < 4; ++mf)                                           \
      a[mf] = *(const s16x8*)(&Zs[mf * 16 + l15][(KS) * 32 + lhi * 8]);      \
    _Pragma("unroll")                                                        \
    for (int mf = 0; mf < 4; ++mf)                                           \
      _Pragma("unroll")                                                      \
      for (int nf = 0; nf < 2; ++nf)                                         \
        acc2[mf][nf] = __builtin_amdgcn_mfma_f32_16x16x32_bf16(              \
            a[mf], REGS[nf], acc2[mf][nf], 0, 0, 0);                         \
    if ((G) * 8 + (KS) + 4 < 32) P2B(REGS, (G) * 8 + (KS) + 4);              \
  }

  for (int g = 0; g < 4; ++g) {        // 32-proto chunks of this wave's 128
    f32x4 acc2[4][2];
#pragma unroll
    for (int mf = 0; mf < 4; ++mf)
#pragma unroll
      for (int nf = 0; nf < 2; ++nf) acc2[mf][nf] = (f32x4)0.0f;

    P2KS(0, g, brA);
    P2KS(1, g, brB);
    P2KS(2, g, brC);
    P2KS(3, g, brD);
    P2KS(4, g, brA);
    P2KS(5, g, brB);
    P2KS(6, g, brC);
    P2KS(7, g, brD);

    // ---- epilogue for this 32-proto chunk ----
    float ppv[2];
#pragma unroll
    for (int nf = 0; nf < 2; ++nf) ppv[nf] = ppb[g * 32 + nf * 16 + l15];
#pragma unroll
    for (int mf = 0; mf < 4; ++mf)
#pragma unroll
      for (int r = 0; r < 4; ++r) {
        const size_t rowoff = (size_t)(mf * 16 + lhi * 4 + r) * NPROTO;
#pragma unroll
        for (int nf = 0; nf < 2; ++nf) {
          float d2 = fmaxf(1.0f + ppv[nf] - 2.0f * acc2[mf][nf][r], 0.0f);
          outb[rowoff + g * 32 + nf * 16 + l15] = -sqrtf(d2);
        }
      }
  }
#undef P2KS
#undef P2B
}

extern "C" void kernel_launch(void* const* d_in, const int* in_sizes, int n_in,
                              void* d_out, int out_size, void* d_ws, size_t ws_size,
                              hipStream_t stream) {
  const float* X     = (const float*)d_in[0];  // [16384,1024]
  const float* mean  = (const float*)d_in[1];  // [1024]
  const float* proj  = (const float*)d_in[2];  // [1024,256]
  const float* proto = (const float*)d_in[3];  // [2048,256]
  float* out = (float*)d_out;                  // [16384,2048]

  char* ws = (char*)d_ws;
  // workspace layout (~1.5 MB total)
  size_t off = 0;
  unsigned short* projT_sw = (unsigned short*)(ws + off); off += (size_t)DIM * DP * 2;    // 512 KB
  unsigned short* Pb_sw    = (unsigned short*)(ws + off); off += (size_t)NPROTO * DP * 2; // 1 MB
  float* pp                = (float*)(ws + off);          off += (size_t)NPROTO * 4;      // 8 KB

  hipLaunchKernelGGL(k_prep, dim3(384 + NPROTO), dim3(256), 0, stream,
                     proj, proto, projT_sw, Pb_sw, pp);
  hipLaunchKernelGGL(k_fused, dim3(N_ROWS / 64), dim3(1024), 0, stream,
                     X, mean, projT_sw, Pb_sw, pp, out);
}